// Round 1
// baseline (1103.335 us; speedup 1.0000x reference)
//
#include <hip/hip_runtime.h>

typedef __bf16 bf16x8 __attribute__((ext_vector_type(8)));
typedef float  f32x4  __attribute__((ext_vector_type(4)));

#define IN_F  4096
#define OUT_F 4096
#define TM 128
#define TN 128
#define BK 32

// ---- fp32 -> bf16 (RNE) pack helpers --------------------------------------
__device__ inline unsigned int pk_bf16(float a, float b) {
  unsigned int ua = __float_as_uint(a);
  unsigned int ub = __float_as_uint(b);
  ua = (ua + 0x7FFFu + ((ua >> 16) & 1u)) >> 16;
  ub = (ub + 0x7FFFu + ((ub >> 16) & 1u)) >> 16;
  return ua | (ub << 16);
}

// ---- prep kernels ----------------------------------------------------------
__global__ void copy_f32x4(const float4* __restrict__ src, float4* __restrict__ dst, int n4) {
  int i = blockIdx.x * 256 + threadIdx.x;
  if (i < n4) dst[i] = src[i];
}

__global__ void scatter_add_k(float* __restrict__ w, const int* __restrict__ idx,
                              const float* __restrict__ v, int nnz) {
  int i = blockIdx.x * 256 + threadIdx.x;
  if (i < nnz) atomicAdd(w + idx[i], v[i]);
}

// 8 floats -> 8 bf16 per thread (16B store)
__global__ void cvt_f32_bf16_x8(const float4* __restrict__ src, uint4* __restrict__ dst, int n8) {
  int i = blockIdx.x * 256 + threadIdx.x;
  if (i >= n8) return;
  float4 a = src[2 * i];
  float4 b = src[2 * i + 1];
  uint4 o;
  o.x = pk_bf16(a.x, a.y);
  o.y = pk_bf16(a.z, a.w);
  o.z = pk_bf16(b.x, b.y);
  o.w = pk_bf16(b.z, b.w);
  dst[i] = o;
}

// ---- bf16 MFMA GEMM: out[m][n] = sum_k Xb[m][k]*Wb[n][k] + bias[n] ---------
// 128x128 tile / block of 256 threads (4 waves, each 64x64 = 4x4 MFMA tiles).
// BK=32 (one 16x16x32 MFMA k-step per staged tile). LDS tiles [128][32] bf16,
// filled lane-linearly by global_load_lds (wave-uniform base + lane*16).
// XOR swizzle on the GLOBAL source column chunk (kc ^ ((row>>1)&3)) makes the
// ds_read_b128 fragment reads 2-way-conflict max (free) without breaking the
// lane-linear LDS fill.
__global__ __launch_bounds__(256, 2) void gemm_bt_bias(
    const unsigned short* __restrict__ Xb,   // [M][K] bf16
    const unsigned short* __restrict__ Wb,   // [N][K] bf16
    const float* __restrict__ bias,          // [N]
    float* __restrict__ out,                 // [M][N] fp32
    int M, int N, int K)
{
  __shared__ unsigned short lds_a[TM * BK];  // 8 KB
  __shared__ unsigned short lds_b[TN * BK];  // 8 KB

  const int t    = threadIdx.x;
  const int wave = t >> 6;
  const int lane = t & 63;
  const int quad = lane >> 4;
  const int l16  = lane & 15;

  const int tile_n = blockIdx.x * TN;
  const int tile_m = blockIdx.y * TM;

  const int wm = (wave >> 1) * 64;   // wave sub-tile origin within 128x128
  const int wn = (wave & 1) * 64;

  f32x4 acc[4][4] = {};

  const unsigned short* Ag = Xb + (size_t)tile_m * K;
  const unsigned short* Bg = Wb + (size_t)tile_n * K;

  // staging decomposition: chunk c = it*256 + t ; LDS row = c>>2 ; LDS kchunk = c&3
  const int c0 = t, c1 = 256 + t;
  const int row0 = c0 >> 2, row1 = c1 >> 2;
  const int kc0 = (((c0 & 3) ^ ((row0 >> 1) & 3)) * 8);   // swizzled source column
  const int kc1 = (((c1 & 3) ^ ((row1 >> 1) & 3)) * 8);

  for (int kb = 0; kb < K; kb += BK) {
    __syncthreads();  // previous iteration's ds_reads done before overwrite
    __builtin_amdgcn_global_load_lds(
        (const __attribute__((address_space(1))) unsigned int*)(Ag + (size_t)row0 * K + kb + kc0),
        (__attribute__((address_space(3))) unsigned int*)(lds_a + c0 * 8), 16, 0, 0);
    __builtin_amdgcn_global_load_lds(
        (const __attribute__((address_space(1))) unsigned int*)(Ag + (size_t)row1 * K + kb + kc1),
        (__attribute__((address_space(3))) unsigned int*)(lds_a + c1 * 8), 16, 0, 0);
    __builtin_amdgcn_global_load_lds(
        (const __attribute__((address_space(1))) unsigned int*)(Bg + (size_t)row0 * K + kb + kc0),
        (__attribute__((address_space(3))) unsigned int*)(lds_b + c0 * 8), 16, 0, 0);
    __builtin_amdgcn_global_load_lds(
        (const __attribute__((address_space(1))) unsigned int*)(Bg + (size_t)row1 * K + kb + kc1),
        (__attribute__((address_space(3))) unsigned int*)(lds_b + c1 * 8), 16, 0, 0);
    __syncthreads();  // compiler drains vmcnt(0) here — staging visible

    bf16x8 af[4], bfr[4];
#pragma unroll
    for (int i = 0; i < 4; ++i) {
      const int ra = wm + i * 16 + l16;                 // LDS row for A frag
      const int rb = wn + i * 16 + l16;                 // LDS row for B frag
      const int ca = (quad ^ ((ra >> 1) & 3)) * 8;      // un-swizzle: want k-chunk=quad
      const int cb = (quad ^ ((rb >> 1) & 3)) * 8;
      af[i]  = *(const bf16x8*)&lds_a[ra * BK + ca];    // ds_read_b128
      bfr[i] = *(const bf16x8*)&lds_b[rb * BK + cb];
    }
#pragma unroll
    for (int i = 0; i < 4; ++i)
#pragma unroll
      for (int j = 0; j < 4; ++j)
        acc[i][j] = __builtin_amdgcn_mfma_f32_16x16x32_bf16(af[i], bfr[j], acc[i][j], 0, 0, 0);
  }

  // epilogue: D lane mapping col = lane&15, row = quad*4 + reg  (m89/m91-verified)
#pragma unroll
  for (int j = 0; j < 4; ++j) {
    const int n = tile_n + wn + j * 16 + l16;
    const float bv = bias[n];
#pragma unroll
    for (int i = 0; i < 4; ++i) {
      const int m0 = tile_m + wm + i * 16 + quad * 4;
#pragma unroll
      for (int r = 0; r < 4; ++r) {
        out[(size_t)(m0 + r) * N + n] = acc[i][j][r] + bv;
      }
    }
  }
}

// ---- launch ----------------------------------------------------------------
extern "C" void kernel_launch(void* const* d_in, const int* in_sizes, int n_in,
                              void* d_out, int out_size, void* d_ws, size_t ws_size,
                              hipStream_t stream) {
  const float* x    = (const float*)d_in[0];  // [8,2048,4096]
  const float* dw   = (const float*)d_in[1];  // [4096,4096]
  const float* bias = (const float*)d_in[2];  // [4096]
  const float* sv   = (const float*)d_in[3];  // [NNZ]
  const int*   idx  = (const int*)d_in[4];    // [NNZ] sorted flat indices
  float* out = (float*)d_out;

  const int K = IN_F, N = OUT_F;
  const int M   = in_sizes[0] / K;   // 16384 tokens
  const int nnz = in_sizes[3];
  const int WN  = N * K;             // 16,777,216

  // workspace: [W fp32 64MB][W bf16 32MB][X bf16 128MB] = 224 MB
  float*          ws_w  = (float*)d_ws;
  unsigned short* ws_wb = (unsigned short*)((char*)d_ws + (size_t)WN * 4);
  unsigned short* ws_xb = (unsigned short*)((char*)d_ws + (size_t)WN * 4 + (size_t)WN * 2);

  // 1) copy dense W to scratch (fp32)
  copy_f32x4<<<WN / 4 / 256, 256, 0, stream>>>((const float4*)dw, (float4*)ws_w, WN / 4);
  // 2) scatter-add sparse deltas (duplicates handled by atomic, matches .at[].add)
  scatter_add_k<<<(nnz + 255) / 256, 256, 0, stream>>>(ws_w, idx, sv, nnz);
  // 3) W fp32 -> bf16
  cvt_f32_bf16_x8<<<WN / 8 / 256, 256, 0, stream>>>((const float4*)ws_w, (uint4*)ws_wb, WN / 8);
  // 4) X fp32 -> bf16
  const int xn = in_sizes[0];
  cvt_f32_bf16_x8<<<xn / 8 / 256, 256, 0, stream>>>((const float4*)x, (uint4*)ws_xb, xn / 8);
  // 5) bf16 MFMA GEMM + bias
  dim3 grid(N / TN, M / TM);  // (32, 128)
  gemm_bt_bias<<<grid, 256, 0, stream>>>(ws_xb, ws_wb, bias, out, M, N, K);
}